// Round 4
// baseline (817.963 us; speedup 1.0000x reference)
//
#include <hip/hip_runtime.h>

// DGMRF forward, L layers, T=16 channels — binned counting-sort build +
// LDS-scatter layers. Zero global atomics on the hot path.
//
// Layer math (factored): S[d] = sum_{e: dst(e)=d} x[src(e)]  (unweighted)
//   x_new[n] = sw * x[n] * deg[n]^dp + nw * S[n] * deg[n]^(dp-1) + bias
// dp = sigmoid(gamma[l]), sw = exp(alpha1[l]), nw = sw * tanh(alpha1[l]).
// deg = OUT-degree over edge_index[0].
//
// Nodes are grouped into bins of 128. Edges are counting-sorted into per-bin
// regions (dst-binned pairs for aggregation, src-binned local ids for the
// degree histogram) using per-block LDS histograms + a block-column scan —
// no global atomics. Each layer runs one block per bin with a 16x128 f32
// accumulator in LDS (LDS atomics, ~2-way bank alias = free).

#define TCH 16
#define BBITS 7
#define BINW (1 << BBITS)      // 128 nodes per bin
#define BLK 256
#define SPILL_CAP 65536

// ---------- per-block bin histograms (dst and src) ----------
__global__ void k_hist(const int* __restrict__ src, const int* __restrict__ dst,
                       int* __restrict__ Hd, int* __restrict__ Hs,
                       int E, int NB, int CHUNK) {
    extern __shared__ int sm[];                 // cd[NB], cs[NB]
    int* cd = sm; int* cs2 = sm + NB;
    for (int i = threadIdx.x; i < 2 * NB; i += blockDim.x) sm[i] = 0;
    __syncthreads();
    int beg = blockIdx.x * CHUNK;
    int end = beg + CHUNK; if (end > E) end = E;
    for (int i = beg + threadIdx.x; i < end; i += blockDim.x) {
        atomicAdd(&cd[dst[i] >> BBITS], 1);
        atomicAdd(&cs2[src[i] >> BBITS], 1);
    }
    __syncthreads();
    int* hd = Hd + (size_t)blockIdx.x * NB;
    int* hs = Hs + (size_t)blockIdx.x * NB;
    for (int b = threadIdx.x; b < NB; b += blockDim.x) { hd[b] = cd[b]; hs[b] = cs2[b]; }
}

// ---------- column scan over blocks, one block per bin (NBLK <= 4*BLK) ----
__global__ void k_scanb(const int* __restrict__ H, int* __restrict__ off,
                        int* __restrict__ cnt, int NB, int NBLK) {
    __shared__ int ss[BLK];
    int bin = blockIdx.x;
    int t = threadIdx.x;
    int v[4];
    int sum = 0;
#pragma unroll
    for (int j = 0; j < 4; ++j) {
        int b = t * 4 + j;
        v[j] = (b < NBLK) ? H[(size_t)b * NB + bin] : 0;
        sum += v[j];
    }
    ss[t] = sum;
    __syncthreads();
    for (int o = 1; o < BLK; o <<= 1) {
        int u = (t >= o) ? ss[t - o] : 0;
        __syncthreads();
        ss[t] += u;
        __syncthreads();
    }
    int base = ss[t] - sum;                      // exclusive over 4-groups
#pragma unroll
    for (int j = 0; j < 4; ++j) {
        int b = t * 4 + j;
        if (b < NBLK) off[(size_t)b * NB + bin] = base;
        base += v[j];
    }
    if (t == BLK - 1) cnt[bin] = ss[BLK - 1];
}

// ---------- place edges into bin regions (LDS rank atomics only) ----------
__global__ void k_place(const int* __restrict__ src, const int* __restrict__ dst,
                        const int* __restrict__ offd, const int* __restrict__ offs,
                        int* __restrict__ dpairs, unsigned char* __restrict__ srcb,
                        int* __restrict__ spill_cnt, int* __restrict__ spill_d,
                        int* __restrict__ spill_s,
                        int E, int NB, int CHUNK, int CAPB) {
    extern __shared__ int sm[];                 // od[NB], os[NB], rd[NB], rs[NB]
    int* od = sm; int* os = sm + NB; int* rd = sm + 2 * NB; int* rs = sm + 3 * NB;
    for (int b = threadIdx.x; b < NB; b += blockDim.x) {
        od[b] = offd[(size_t)blockIdx.x * NB + b];
        os[b] = offs[(size_t)blockIdx.x * NB + b];
        rd[b] = 0; rs[b] = 0;
    }
    __syncthreads();
    int beg = blockIdx.x * CHUNK;
    int end = beg + CHUNK; if (end > E) end = E;
    for (int i = beg + threadIdx.x; i < end; i += blockDim.x) {
        int s = src[i], d = dst[i];
        int bd = d >> BBITS, bs = s >> BBITS;
        int pd = od[bd] + atomicAdd(&rd[bd], 1);
        if (pd < CAPB) dpairs[(size_t)bd * CAPB + pd] = ((d & (BINW - 1)) << 25) | s;
        else { int p = atomicAdd(&spill_cnt[0], 1);
               if (p < SPILL_CAP) { spill_d[2 * p] = d; spill_d[2 * p + 1] = s; } }
        int ps = os[bs] + atomicAdd(&rs[bs], 1);
        if (ps < CAPB) srcb[(size_t)bs * CAPB + ps] = (unsigned char)(s & (BINW - 1));
        else { int p = atomicAdd(&spill_cnt[1], 1);
               if (p < SPILL_CAP) spill_s[p] = s; }
    }
}

// ---------- out-degree from src-binned local ids ----------
__global__ void k_deg(const unsigned char* __restrict__ srcb, const int* __restrict__ cnts,
                      int* __restrict__ deg, int N, int CAPB) {
    __shared__ int h[BINW];
    int bin = blockIdx.x;
    if (threadIdx.x < BINW) h[threadIdx.x] = 0;
    __syncthreads();
    int m = cnts[bin]; if (m > CAPB) m = CAPB;
    const unsigned char* p = srcb + (size_t)bin * CAPB;
    for (int i = threadIdx.x; i < m; i += blockDim.x)
        atomicAdd(&h[p[i]], 1);
    __syncthreads();
    int n = (bin << BBITS) + threadIdx.x;
    if (threadIdx.x < BINW && n < N) deg[n] = h[threadIdx.x];
}

__global__ void k_deg_spill(const int* __restrict__ spill_cnt, const int* __restrict__ spill_s,
                            int* __restrict__ deg) {
    int total = spill_cnt[1]; if (total > SPILL_CAP) total = SPILL_CAP;
    int stride = gridDim.x * blockDim.x;
    for (int i = blockIdx.x * blockDim.x + threadIdx.x; i < total; i += stride)
        atomicAdd(&deg[spill_s[i]], 1);
}

// ---------- x [T][N] -> xt [N][T] ----------
__global__ void k_tin(const float* __restrict__ x, float* __restrict__ xt, int N) {
    int n = blockIdx.x * blockDim.x + threadIdx.x;
    if (n >= N) return;
    float v[TCH];
#pragma unroll
    for (int t = 0; t < TCH; ++t) v[t] = x[(size_t)t * N + n];
    float4* o = reinterpret_cast<float4*>(xt + (size_t)n * TCH);
    o[0] = make_float4(v[0],  v[1],  v[2],  v[3]);
    o[1] = make_float4(v[4],  v[5],  v[6],  v[7]);
    o[2] = make_float4(v[8],  v[9],  v[10], v[11]);
    o[3] = make_float4(v[12], v[13], v[14], v[15]);
}

// ---------- layer: LDS-scatter aggregate + fused combine ----------
__global__ void k_layer(const float* __restrict__ xin, float* __restrict__ xout,
                        const int* __restrict__ dpairs, const int* __restrict__ cntd,
                        const int* __restrict__ deg,
                        const float* __restrict__ a1p, const float* __restrict__ gp,
                        const float* __restrict__ bp, int l, int N, int CAPB,
                        int last, float* __restrict__ out) {
    __shared__ float S[TCH * BINW];              // [t][dl]: bank = dl%32 (random ~2-way)
    int bin = blockIdx.x;
    for (int i = threadIdx.x; i < TCH * BINW; i += blockDim.x) S[i] = 0.f;
    __syncthreads();
    int m = cntd[bin]; if (m > CAPB) m = CAPB;
    const int* pp = dpairs + (size_t)bin * CAPB;
    for (int i = threadIdx.x; i < m; i += blockDim.x) {
        int w = pp[i];
        int s = w & 0x1FFFFFF;
        int dl = ((unsigned)w) >> 25;
        const float4* xs = reinterpret_cast<const float4*>(xin + (size_t)s * TCH);
        float4 a = xs[0], b4 = xs[1], c = xs[2], d4 = xs[3];
        atomicAdd(&S[0  * BINW + dl], a.x);  atomicAdd(&S[1  * BINW + dl], a.y);
        atomicAdd(&S[2  * BINW + dl], a.z);  atomicAdd(&S[3  * BINW + dl], a.w);
        atomicAdd(&S[4  * BINW + dl], b4.x); atomicAdd(&S[5  * BINW + dl], b4.y);
        atomicAdd(&S[6  * BINW + dl], b4.z); atomicAdd(&S[7  * BINW + dl], b4.w);
        atomicAdd(&S[8  * BINW + dl], c.x);  atomicAdd(&S[9  * BINW + dl], c.y);
        atomicAdd(&S[10 * BINW + dl], c.z);  atomicAdd(&S[11 * BINW + dl], c.w);
        atomicAdd(&S[12 * BINW + dl], d4.x); atomicAdd(&S[13 * BINW + dl], d4.y);
        atomicAdd(&S[14 * BINW + dl], d4.z); atomicAdd(&S[15 * BINW + dl], d4.w);
    }
    __syncthreads();

    float a1 = a1p[l], g = gp[l], bi = bp[l];
    float dp = 1.0f / (1.0f + expf(-g));
    float sw = expf(a1);
    float nw = sw * tanhf(a1);

    int nl = threadIdx.x >> 1;                   // 0..127
    int q2 = threadIdx.x & 1;                    // half: channels q2*8..q2*8+7
    int n = (bin << BBITS) + nl;
    if (n >= N) return;
    float ldg = logf((float)deg[n]);
    float cs = sw * expf(dp * ldg);
    float cn = nw * expf((dp - 1.0f) * ldg);

    const float4* xv = reinterpret_cast<const float4*>(xin + (size_t)n * TCH + q2 * 8);
    float4 x0 = xv[0], x1 = xv[1];
    float r[8];
    r[0] = cs * x0.x + cn * S[(q2 * 8 + 0) * BINW + nl] + bi;
    r[1] = cs * x0.y + cn * S[(q2 * 8 + 1) * BINW + nl] + bi;
    r[2] = cs * x0.z + cn * S[(q2 * 8 + 2) * BINW + nl] + bi;
    r[3] = cs * x0.w + cn * S[(q2 * 8 + 3) * BINW + nl] + bi;
    r[4] = cs * x1.x + cn * S[(q2 * 8 + 4) * BINW + nl] + bi;
    r[5] = cs * x1.y + cn * S[(q2 * 8 + 5) * BINW + nl] + bi;
    r[6] = cs * x1.z + cn * S[(q2 * 8 + 6) * BINW + nl] + bi;
    r[7] = cs * x1.w + cn * S[(q2 * 8 + 7) * BINW + nl] + bi;

    if (last) {
#pragma unroll
        for (int j = 0; j < 8; ++j) out[(size_t)(q2 * 8 + j) * N + n] = r[j];
    } else {
        float4* o = reinterpret_cast<float4*>(xout + (size_t)n * TCH + q2 * 8);
        o[0] = make_float4(r[0], r[1], r[2], r[3]);
        o[1] = make_float4(r[4], r[5], r[6], r[7]);
    }
}

// ---------- fix-up for spilled dst edges (normally empty) ----------
__global__ void k_spill(const int* __restrict__ spill_cnt, const int* __restrict__ spill_d,
                        const float* __restrict__ xin, float* __restrict__ xout,
                        const int* __restrict__ deg,
                        const float* __restrict__ a1p, const float* __restrict__ gp,
                        int l, int N, int last, float* __restrict__ out) {
    int total = spill_cnt[0]; if (total > SPILL_CAP) total = SPILL_CAP;
    int stride = gridDim.x * blockDim.x;
    float a1 = a1p[l], g = gp[l];
    float dp = 1.0f / (1.0f + expf(-g));
    float nw = expf(a1) * tanhf(a1);
    for (int p = blockIdx.x * blockDim.x + threadIdx.x; p < total; p += stride) {
        int d = spill_d[2 * p], s = spill_d[2 * p + 1];
        float cn = nw * expf((dp - 1.0f) * logf((float)deg[d]));
#pragma unroll
        for (int t = 0; t < TCH; ++t) {
            float v = cn * xin[(size_t)s * TCH + t];
            if (last) atomicAdd(&out[(size_t)t * N + d], v);
            else      atomicAdd(&xout[(size_t)d * TCH + t], v);
        }
    }
}

extern "C" void kernel_launch(void* const* d_in, const int* in_sizes, int n_in,
                              void* d_out, int out_size, void* d_ws, size_t ws_size,
                              hipStream_t stream) {
    const float* x      = (const float*)d_in[0];
    const int*   ei     = (const int*)d_in[1];
    const float* alpha1 = (const float*)d_in[2];
    // d_in[3] = alpha2: UNUSED (reference's alpha2 property returns alpha1)
    const float* gamma  = (const float*)d_in[4];
    const float* bias   = (const float*)d_in[5];
    float* out = (float*)d_out;

    const int N = in_sizes[0] / TCH;
    const int E = in_sizes[1] / 2;
    const int L = in_sizes[2];
    const int* src = ei;
    const int* dst = ei + E;

    const int NB = (N + BINW - 1) >> BBITS;
    int CHUNK = 4096;
    int NBLK = (E + CHUNK - 1) / CHUNK;
    while (NBLK > 4 * BLK) { CHUNK *= 2; NBLK = (E + CHUNK - 1) / CHUNK; }

    auto align = [](size_t v) { return (v + 255) & ~(size_t)255; };
    char* ws = (char*)d_ws;
    size_t off = 0;
    int* deg     = (int*)(ws + off); off += align((size_t)N * 4);
    int* cntd    = (int*)(ws + off); off += align((size_t)NB * 4);
    int* cnts    = (int*)(ws + off); off += align((size_t)NB * 4);
    int* Hd      = (int*)(ws + off); off += align((size_t)NBLK * NB * 4);
    int* Hs      = (int*)(ws + off); off += align((size_t)NBLK * NB * 4);
    int* offd    = (int*)(ws + off); off += align((size_t)NBLK * NB * 4);
    int* offs    = (int*)(ws + off); off += align((size_t)NBLK * NB * 4);
    int* spill_c = (int*)(ws + off); off += 256;
    int* spill_d = (int*)(ws + off); off += align((size_t)SPILL_CAP * 8);
    int* spill_s = (int*)(ws + off); off += align((size_t)SPILL_CAP * 4);
    float* xt0   = (float*)(ws + off); off += align((size_t)N * TCH * 4);
    float* xt1   = (float*)(ws + off); off += align((size_t)N * TCH * 4);
    // bin capacity: avg + slack, clamped to what remains of the workspace
    long long avg = ((long long)E * BINW + N - 1) / N;     // ~4096
    int CAPB = (int)(avg + avg / 8 + 128);
    size_t rem = (ws_size > off) ? (ws_size - off) : 0;
    size_t cap_fit = rem / ((size_t)NB * 5 + 8);
    if ((size_t)CAPB > cap_fit) CAPB = (int)cap_fit;
    if (CAPB < 1) CAPB = 1;
    int* dpairs  = (int*)(ws + off); off += align((size_t)NB * CAPB * 4);
    unsigned char* srcb = (unsigned char*)(ws + off);

    dim3 b(BLK), gN((N + BLK - 1) / BLK);

    hipMemsetAsync(spill_c, 0, 256, stream);
    k_hist <<<dim3(NBLK), b, 2 * NB * 4, stream>>>(src, dst, Hd, Hs, E, NB, CHUNK);
    k_scanb<<<dim3(NB),   b, 0,          stream>>>(Hd, offd, cntd, NB, NBLK);
    k_scanb<<<dim3(NB),   b, 0,          stream>>>(Hs, offs, cnts, NB, NBLK);
    k_place<<<dim3(NBLK), b, 4 * NB * 4, stream>>>(src, dst, offd, offs, dpairs, srcb,
                                                   spill_c, spill_d, spill_s,
                                                   E, NB, CHUNK, CAPB);
    k_deg  <<<dim3(NB),   b, 0,          stream>>>(srcb, cnts, deg, N, CAPB);
    k_deg_spill<<<dim3(16), b, 0,        stream>>>(spill_c, spill_s, deg);
    k_tin  <<<gN,         b, 0,          stream>>>(x, xt0, N);

    float* xin = xt0;
    float* xo  = xt1;
    for (int l = 0; l < L; ++l) {
        int last = (l == L - 1) ? 1 : 0;
        k_layer<<<dim3(NB), b, 0, stream>>>(xin, xo, dpairs, cntd, deg,
                                            alpha1, gamma, bias, l, N, CAPB, last, out);
        k_spill<<<dim3(16), b, 0, stream>>>(spill_c, spill_d, xin, xo, deg,
                                            alpha1, gamma, l, N, last, out);
        float* tmp = xin; xin = xo; xo = tmp;
    }
}

// Round 5
// 245.069 us; speedup vs baseline: 3.3377x; 3.3377x over previous
//
#include <hip/hip_runtime.h>

// DGMRF forward, L layers, T=16 channels.
// Binned counting-sort build (no global atomics) -> exact per-node CSR ->
// PULL layers (register accumulation, no atomics at all on the hot path).
//
// Layer math (factored): S[d] = sum_{e: dst(e)=d} x[src(e)]  (unweighted)
//   x_new[n] = sw * x[n] * deg[n]^dp + nw * S[n] * deg[n]^(dp-1) + bias
// dp = sigmoid(gamma[l]), sw = exp(alpha1[l]), nw = sw * tanh(alpha1[l]).
// deg = OUT-degree over edge_index[0].

#define TCH 16
#define BBITS 7
#define BINW (1 << BBITS)      // 128 nodes per bin
#define BLK 256
#define SPILL_CAP 65536

// ---------- per-block bin histograms (dst and src) ----------
__global__ void k_hist(const int* __restrict__ src, const int* __restrict__ dst,
                       int* __restrict__ Hd, int* __restrict__ Hs,
                       int E, int NB, int CHUNK) {
    extern __shared__ int sm[];                 // cd[NB], cs[NB]
    int* cd = sm; int* cs2 = sm + NB;
    for (int i = threadIdx.x; i < 2 * NB; i += blockDim.x) sm[i] = 0;
    __syncthreads();
    int beg = blockIdx.x * CHUNK;
    int end = beg + CHUNK; if (end > E) end = E;
    for (int i = beg + threadIdx.x; i < end; i += blockDim.x) {
        atomicAdd(&cd[dst[i] >> BBITS], 1);
        atomicAdd(&cs2[src[i] >> BBITS], 1);
    }
    __syncthreads();
    int* hd = Hd + (size_t)blockIdx.x * NB;
    int* hs = Hs + (size_t)blockIdx.x * NB;
    for (int b = threadIdx.x; b < NB; b += blockDim.x) { hd[b] = cd[b]; hs[b] = cs2[b]; }
}

// ---------- column scan over blocks, one block per bin (NBLK <= 4*BLK) ----
__global__ void k_scanb(const int* __restrict__ H, int* __restrict__ off,
                        int* __restrict__ cnt, int NB, int NBLK) {
    __shared__ int ss[BLK];
    int bin = blockIdx.x;
    int t = threadIdx.x;
    int v[4];
    int sum = 0;
#pragma unroll
    for (int j = 0; j < 4; ++j) {
        int b = t * 4 + j;
        v[j] = (b < NBLK) ? H[(size_t)b * NB + bin] : 0;
        sum += v[j];
    }
    ss[t] = sum;
    __syncthreads();
    for (int o = 1; o < BLK; o <<= 1) {
        int u = (t >= o) ? ss[t - o] : 0;
        __syncthreads();
        ss[t] += u;
        __syncthreads();
    }
    int base = ss[t] - sum;                      // exclusive over 4-groups
#pragma unroll
    for (int j = 0; j < 4; ++j) {
        int b = t * 4 + j;
        if (b < NBLK) off[(size_t)b * NB + bin] = base;
        base += v[j];
    }
    if (t == BLK - 1) cnt[bin] = ss[BLK - 1];
}

// ---------- place edges into bin regions (LDS rank atomics only) ----------
__global__ void k_place(const int* __restrict__ src, const int* __restrict__ dst,
                        const int* __restrict__ offd, const int* __restrict__ offs,
                        int* __restrict__ dpairs, unsigned char* __restrict__ srcb,
                        int* __restrict__ spill_cnt, int* __restrict__ spill_d,
                        int* __restrict__ spill_s,
                        int E, int NB, int CHUNK, int CAPB) {
    extern __shared__ int sm[];                 // od[NB], os[NB], rd[NB], rs[NB]
    int* od = sm; int* os = sm + NB; int* rd = sm + 2 * NB; int* rs = sm + 3 * NB;
    for (int b = threadIdx.x; b < NB; b += blockDim.x) {
        od[b] = offd[(size_t)blockIdx.x * NB + b];
        os[b] = offs[(size_t)blockIdx.x * NB + b];
        rd[b] = 0; rs[b] = 0;
    }
    __syncthreads();
    int beg = blockIdx.x * CHUNK;
    int end = beg + CHUNK; if (end > E) end = E;
    for (int i = beg + threadIdx.x; i < end; i += blockDim.x) {
        int s = src[i], d = dst[i];
        int bd = d >> BBITS, bs = s >> BBITS;
        int pd = od[bd] + atomicAdd(&rd[bd], 1);
        if (pd < CAPB) dpairs[(size_t)bd * CAPB + pd] = ((d & (BINW - 1)) << 25) | s;
        else { int p = atomicAdd(&spill_cnt[0], 1);
               if (p < SPILL_CAP) { spill_d[2 * p] = d; spill_d[2 * p + 1] = s; } }
        int ps = os[bs] + atomicAdd(&rs[bs], 1);
        if (ps < CAPB) srcb[(size_t)bs * CAPB + ps] = (unsigned char)(s & (BINW - 1));
        else { int p = atomicAdd(&spill_cnt[1], 1);
               if (p < SPILL_CAP) spill_s[p] = s; }
    }
}

// ---------- out-degree from src-binned local ids ----------
__global__ void k_deg(const unsigned char* __restrict__ srcb, const int* __restrict__ cnts,
                      int* __restrict__ deg, int N, int CAPB) {
    __shared__ int h[BINW];
    int bin = blockIdx.x;
    if (threadIdx.x < BINW) h[threadIdx.x] = 0;
    __syncthreads();
    int m = cnts[bin]; if (m > CAPB) m = CAPB;
    const unsigned char* p = srcb + (size_t)bin * CAPB;
    for (int i = threadIdx.x; i < m; i += blockDim.x)
        atomicAdd(&h[p[i]], 1);
    __syncthreads();
    int n = (bin << BBITS) + threadIdx.x;
    if (threadIdx.x < BINW && n < N) deg[n] = h[threadIdx.x];
}

__global__ void k_deg_spill(const int* __restrict__ spill_cnt, const int* __restrict__ spill_s,
                            int* __restrict__ deg) {
    int total = spill_cnt[1]; if (total > SPILL_CAP) total = SPILL_CAP;
    int stride = gridDim.x * blockDim.x;
    for (int i = blockIdx.x * blockDim.x + threadIdx.x; i < total; i += stride)
        atomicAdd(&deg[spill_s[i]], 1);
}

// ---------- per-bin counting sort: dpairs -> exact per-node CSR ----------
__global__ void k_binsort(const int* __restrict__ dpairs, const int* __restrict__ cntd,
                          int* __restrict__ adj, int* __restrict__ rptr,
                          int* __restrict__ rcnt, int N, int CAPB) {
    __shared__ int h[BINW];    // per-local-node in-degree
    __shared__ int o[BINW];    // exclusive scan
    __shared__ int rk[BINW];   // placement cursors
    int bin = blockIdx.x;
    int t = threadIdx.x;
    if (t < BINW) { h[t] = 0; rk[t] = 0; }
    __syncthreads();
    int m = cntd[bin]; if (m > CAPB) m = CAPB;
    const int* pp = dpairs + (size_t)bin * CAPB;
    for (int i = t; i < m; i += blockDim.x)
        atomicAdd(&h[((unsigned)pp[i]) >> 25], 1);
    __syncthreads();
    // inclusive scan of h over 128 entries (threads 0..127 active per step)
    if (t < BINW) o[t] = h[t];
    __syncthreads();
    for (int s = 1; s < BINW; s <<= 1) {
        int v = 0;
        if (t < BINW && t >= s) v = o[t - s];
        __syncthreads();
        if (t < BINW && t >= s) o[t] += v;
        __syncthreads();
    }
    int binbase = bin * CAPB;
    if (t < BINW) {
        int excl = o[t] - h[t];
        o[t] = excl;
        int n = (bin << BBITS) + t;
        if (n < N) { rptr[n] = binbase + excl; rcnt[n] = h[t]; }
    }
    __syncthreads();
    for (int i = t; i < m; i += blockDim.x) {
        int w = pp[i];
        int dl = ((unsigned)w) >> 25;
        int s  = w & 0x1FFFFFF;
        int r = atomicAdd(&rk[dl], 1);
        adj[binbase + o[dl] + r] = s;
    }
}

// ---------- x [T][N] -> xt [N][T] ----------
__global__ void k_tin(const float* __restrict__ x, float* __restrict__ xt, int N) {
    int n = blockIdx.x * blockDim.x + threadIdx.x;
    if (n >= N) return;
    float v[TCH];
#pragma unroll
    for (int t = 0; t < TCH; ++t) v[t] = x[(size_t)t * N + n];
    float4* o = reinterpret_cast<float4*>(xt + (size_t)n * TCH);
    o[0] = make_float4(v[0],  v[1],  v[2],  v[3]);
    o[1] = make_float4(v[4],  v[5],  v[6],  v[7]);
    o[2] = make_float4(v[8],  v[9],  v[10], v[11]);
    o[3] = make_float4(v[12], v[13], v[14], v[15]);
}

// ---------- layer: pull over CSR + fused combine ----------
// 4 threads per node, one float4 quarter each; 4-wide unrolled gather.
__global__ void k_layer(const float* __restrict__ xin, float* __restrict__ xout,
                        const int* __restrict__ rptr, const int* __restrict__ rcnt,
                        const int* __restrict__ adj, const int* __restrict__ deg,
                        const float* __restrict__ a1p, const float* __restrict__ gp,
                        const float* __restrict__ bp, int l, int N,
                        int last, float* __restrict__ out) {
    int tt = blockIdx.x * blockDim.x + threadIdx.x;
    int n = tt >> 2;
    int q = tt & 3;
    if (n >= N) return;
    float a1 = a1p[l], g = gp[l], bi = bp[l];
    float dp = 1.0f / (1.0f + expf(-g));
    float sw = expf(a1);
    float nw = sw * tanhf(a1);

    int b = rptr[n], m = rcnt[n];
    const int* row = adj + b;
    float4 acc0 = make_float4(0.f, 0.f, 0.f, 0.f);
    float4 acc1 = make_float4(0.f, 0.f, 0.f, 0.f);
    int i = 0;
    for (; i + 3 < m; i += 4) {
        int s0 = row[i], s1 = row[i + 1], s2 = row[i + 2], s3 = row[i + 3];
        float4 x0 = reinterpret_cast<const float4*>(xin + (size_t)s0 * TCH)[q];
        float4 x1 = reinterpret_cast<const float4*>(xin + (size_t)s1 * TCH)[q];
        float4 x2 = reinterpret_cast<const float4*>(xin + (size_t)s2 * TCH)[q];
        float4 x3 = reinterpret_cast<const float4*>(xin + (size_t)s3 * TCH)[q];
        acc0.x += x0.x; acc0.y += x0.y; acc0.z += x0.z; acc0.w += x0.w;
        acc1.x += x1.x; acc1.y += x1.y; acc1.z += x1.z; acc1.w += x1.w;
        acc0.x += x2.x; acc0.y += x2.y; acc0.z += x2.z; acc0.w += x2.w;
        acc1.x += x3.x; acc1.y += x3.y; acc1.z += x3.z; acc1.w += x3.w;
    }
    for (; i < m; ++i) {
        int s0 = row[i];
        float4 x0 = reinterpret_cast<const float4*>(xin + (size_t)s0 * TCH)[q];
        acc0.x += x0.x; acc0.y += x0.y; acc0.z += x0.z; acc0.w += x0.w;
    }
    acc0.x += acc1.x; acc0.y += acc1.y; acc0.z += acc1.z; acc0.w += acc1.w;

    float ldg = logf((float)deg[n]);
    float cs = sw * expf(dp * ldg);
    float cn = nw * expf((dp - 1.0f) * ldg);

    float4 xq = reinterpret_cast<const float4*>(xin + (size_t)n * TCH)[q];
    float4 r;
    r.x = cs * xq.x + cn * acc0.x + bi;
    r.y = cs * xq.y + cn * acc0.y + bi;
    r.z = cs * xq.z + cn * acc0.z + bi;
    r.w = cs * xq.w + cn * acc0.w + bi;

    if (last) {
        int t0 = q * 4;
        out[(size_t)(t0 + 0) * N + n] = r.x;
        out[(size_t)(t0 + 1) * N + n] = r.y;
        out[(size_t)(t0 + 2) * N + n] = r.z;
        out[(size_t)(t0 + 3) * N + n] = r.w;
    } else {
        reinterpret_cast<float4*>(xout + (size_t)n * TCH)[q] = r;
    }
}

// ---------- fix-up for spilled dst edges (normally empty) ----------
__global__ void k_spill(const int* __restrict__ spill_cnt, const int* __restrict__ spill_d,
                        const float* __restrict__ xin, float* __restrict__ xout,
                        const int* __restrict__ deg,
                        const float* __restrict__ a1p, const float* __restrict__ gp,
                        int l, int N, int last, float* __restrict__ out) {
    int total = spill_cnt[0]; if (total > SPILL_CAP) total = SPILL_CAP;
    int stride = gridDim.x * blockDim.x;
    float a1 = a1p[l], g = gp[l];
    float dp = 1.0f / (1.0f + expf(-g));
    float nw = expf(a1) * tanhf(a1);
    for (int p = blockIdx.x * blockDim.x + threadIdx.x; p < total; p += stride) {
        int d = spill_d[2 * p], s = spill_d[2 * p + 1];
        float cn = nw * expf((dp - 1.0f) * logf((float)deg[d]));
#pragma unroll
        for (int t = 0; t < TCH; ++t) {
            float v = cn * xin[(size_t)s * TCH + t];
            if (last) atomicAdd(&out[(size_t)t * N + d], v);
            else      atomicAdd(&xout[(size_t)d * TCH + t], v);
        }
    }
}

extern "C" void kernel_launch(void* const* d_in, const int* in_sizes, int n_in,
                              void* d_out, int out_size, void* d_ws, size_t ws_size,
                              hipStream_t stream) {
    const float* x      = (const float*)d_in[0];
    const int*   ei     = (const int*)d_in[1];
    const float* alpha1 = (const float*)d_in[2];
    // d_in[3] = alpha2: UNUSED (reference's alpha2 property returns alpha1)
    const float* gamma  = (const float*)d_in[4];
    const float* bias   = (const float*)d_in[5];
    float* out = (float*)d_out;

    const int N = in_sizes[0] / TCH;
    const int E = in_sizes[1] / 2;
    const int L = in_sizes[2];
    const int* src = ei;
    const int* dst = ei + E;

    const int NB = (N + BINW - 1) >> BBITS;
    int CHUNK = 8192;
    int NBLK = (E + CHUNK - 1) / CHUNK;
    while (NBLK > 4 * BLK) { CHUNK *= 2; NBLK = (E + CHUNK - 1) / CHUNK; }

    auto align = [](size_t v) { return (v + 255) & ~(size_t)255; };
    char* ws = (char*)d_ws;
    size_t off = 0;
    int* deg     = (int*)(ws + off); off += align((size_t)N * 4);
    int* rptr    = (int*)(ws + off); off += align((size_t)N * 4);
    int* rcnt    = (int*)(ws + off); off += align((size_t)N * 4);
    int* cntd    = (int*)(ws + off); off += align((size_t)NB * 4);
    int* cnts    = (int*)(ws + off); off += align((size_t)NB * 4);
    int* Hd      = (int*)(ws + off); off += align((size_t)NBLK * NB * 4);
    int* Hs      = (int*)(ws + off); off += align((size_t)NBLK * NB * 4);
    int* offd    = (int*)(ws + off); off += align((size_t)NBLK * NB * 4);
    int* offs    = (int*)(ws + off); off += align((size_t)NBLK * NB * 4);
    int* spill_c = (int*)(ws + off); off += 256;
    int* spill_d = (int*)(ws + off); off += align((size_t)SPILL_CAP * 8);
    int* spill_s = (int*)(ws + off); off += align((size_t)SPILL_CAP * 4);
    float* xt0   = (float*)(ws + off); off += align((size_t)N * TCH * 4);
    float* xt1   = (float*)(ws + off); off += align((size_t)N * TCH * 4);
    // bin capacity: avg + slack, clamped to fit remaining workspace
    long long avg = ((long long)E * BINW + N - 1) / N;     // ~4096
    int CAPB = (int)(avg + avg / 16 + 64);
    size_t rem = (ws_size > off) ? (ws_size - off) : 0;
    size_t cap_fit = rem / ((size_t)NB * 9 + 8);           // dpairs4 + srcb1 + adj4
    if ((size_t)CAPB > cap_fit) CAPB = (int)cap_fit;
    if (CAPB < 1) CAPB = 1;
    int* dpairs  = (int*)(ws + off); off += align((size_t)NB * CAPB * 4);
    int* adj     = (int*)(ws + off); off += align((size_t)NB * CAPB * 4);
    unsigned char* srcb = (unsigned char*)(ws + off);

    dim3 b(BLK), gN((N + BLK - 1) / BLK);
    dim3 gN4(((size_t)N * 4 + BLK - 1) / BLK);

    hipMemsetAsync(spill_c, 0, 256, stream);
    k_hist   <<<dim3(NBLK), b, 2 * NB * 4, stream>>>(src, dst, Hd, Hs, E, NB, CHUNK);
    k_scanb  <<<dim3(NB),   b, 0,          stream>>>(Hd, offd, cntd, NB, NBLK);
    k_scanb  <<<dim3(NB),   b, 0,          stream>>>(Hs, offs, cnts, NB, NBLK);
    k_place  <<<dim3(NBLK), b, 4 * NB * 4, stream>>>(src, dst, offd, offs, dpairs, srcb,
                                                     spill_c, spill_d, spill_s,
                                                     E, NB, CHUNK, CAPB);
    k_deg    <<<dim3(NB),   b, 0,          stream>>>(srcb, cnts, deg, N, CAPB);
    k_deg_spill<<<dim3(16), b, 0,          stream>>>(spill_c, spill_s, deg);
    k_binsort<<<dim3(NB),   b, 0,          stream>>>(dpairs, cntd, adj, rptr, rcnt, N, CAPB);
    k_tin    <<<gN,         b, 0,          stream>>>(x, xt0, N);

    float* xin = xt0;
    float* xo  = xt1;
    for (int l = 0; l < L; ++l) {
        int last = (l == L - 1) ? 1 : 0;
        k_layer<<<gN4, b, 0, stream>>>(xin, xo, rptr, rcnt, adj, deg,
                                       alpha1, gamma, bias, l, N, last, out);
        k_spill<<<dim3(16), b, 0, stream>>>(spill_c, spill_d, xin, xo, deg,
                                            alpha1, gamma, l, N, last, out);
        float* tmp = xin; xin = xo; xo = tmp;
    }
}

// Round 6
// 239.770 us; speedup vs baseline: 3.4114x; 1.0221x over previous
//
#include <hip/hip_runtime.h>

// DGMRF forward, L layers, T=16 channels.
// Binned counting-sort build (no global atomics) -> exact per-node CSR ->
// PULL layers (register accumulation, no atomics on the hot path).
//
// Layer math (factored): S[d] = sum_{e: dst(e)=d} x[src(e)]  (unweighted)
//   x_new[n] = sw * x[n] * deg[n]^dp + nw * S[n] * deg[n]^(dp-1) + bias
// dp = sigmoid(gamma[l]), sw = exp(alpha1[l]), nw = sw * tanh(alpha1[l]).
// deg = OUT-degree over edge_index[0].
//
// BBITS=8 (256-node bins): per-XCD active write-line set in k_place fits L2,
// eliminating the 10x sector write amplification seen at BBITS=7.

#define TCH 16
#define BBITS 8
#define BINW (1 << BBITS)      // 256 nodes per bin
#define BLK 256
#define SPILL_CAP 65536

// ---------- per-block bin histograms (dst and src) ----------
__global__ void k_hist(const int* __restrict__ src, const int* __restrict__ dst,
                       int* __restrict__ Hd, int* __restrict__ Hs,
                       int E, int NB, int CHUNK) {
    extern __shared__ int sm[];                 // cd[NB], cs[NB]
    int* cd = sm; int* cs2 = sm + NB;
    for (int i = threadIdx.x; i < 2 * NB; i += blockDim.x) sm[i] = 0;
    __syncthreads();
    int beg = blockIdx.x * CHUNK;
    int end = beg + CHUNK; if (end > E) end = E;
    for (int i = beg + threadIdx.x; i < end; i += blockDim.x) {
        atomicAdd(&cd[dst[i] >> BBITS], 1);
        atomicAdd(&cs2[src[i] >> BBITS], 1);
    }
    __syncthreads();
    int* hd = Hd + (size_t)blockIdx.x * NB;
    int* hs = Hs + (size_t)blockIdx.x * NB;
    for (int b = threadIdx.x; b < NB; b += blockDim.x) { hd[b] = cd[b]; hs[b] = cs2[b]; }
}

// ---------- column scan over blocks, one block per bin (NBLK <= 4*BLK) ----
__global__ void k_scanb(const int* __restrict__ H, int* __restrict__ off,
                        int* __restrict__ cnt, int NB, int NBLK) {
    __shared__ int ss[BLK];
    int bin = blockIdx.x;
    int t = threadIdx.x;
    int v[4];
    int sum = 0;
#pragma unroll
    for (int j = 0; j < 4; ++j) {
        int b = t * 4 + j;
        v[j] = (b < NBLK) ? H[(size_t)b * NB + bin] : 0;
        sum += v[j];
    }
    ss[t] = sum;
    __syncthreads();
    for (int o = 1; o < BLK; o <<= 1) {
        int u = (t >= o) ? ss[t - o] : 0;
        __syncthreads();
        ss[t] += u;
        __syncthreads();
    }
    int base = ss[t] - sum;                      // exclusive over 4-groups
#pragma unroll
    for (int j = 0; j < 4; ++j) {
        int b = t * 4 + j;
        if (b < NBLK) off[(size_t)b * NB + bin] = base;
        base += v[j];
    }
    if (t == BLK - 1) cnt[bin] = ss[BLK - 1];
}

// ---------- place edges into bin regions (LDS rank atomics only) ----------
__global__ void k_place(const int* __restrict__ src, const int* __restrict__ dst,
                        const int* __restrict__ offd, const int* __restrict__ offs,
                        int* __restrict__ dpairs, unsigned char* __restrict__ srcb,
                        int* __restrict__ spill_cnt, int* __restrict__ spill_d,
                        int* __restrict__ spill_s,
                        int E, int NB, int CHUNK, int CAPB) {
    extern __shared__ int sm[];                 // od[NB], os[NB], rd[NB], rs[NB]
    int* od = sm; int* os = sm + NB; int* rd = sm + 2 * NB; int* rs = sm + 3 * NB;
    for (int b = threadIdx.x; b < NB; b += blockDim.x) {
        od[b] = offd[(size_t)blockIdx.x * NB + b];
        os[b] = offs[(size_t)blockIdx.x * NB + b];
        rd[b] = 0; rs[b] = 0;
    }
    __syncthreads();
    int beg = blockIdx.x * CHUNK;
    int end = beg + CHUNK; if (end > E) end = E;
    for (int i = beg + threadIdx.x; i < end; i += blockDim.x) {
        int s = src[i], d = dst[i];
        int bd = d >> BBITS, bs = s >> BBITS;
        int pd = od[bd] + atomicAdd(&rd[bd], 1);
        if (pd < CAPB) dpairs[(size_t)bd * CAPB + pd] = ((d & (BINW - 1)) << 24) | s;
        else { int p = atomicAdd(&spill_cnt[0], 1);
               if (p < SPILL_CAP) { spill_d[2 * p] = d; spill_d[2 * p + 1] = s; } }
        int ps = os[bs] + atomicAdd(&rs[bs], 1);
        if (ps < CAPB) srcb[(size_t)bs * CAPB + ps] = (unsigned char)(s & (BINW - 1));
        else { int p = atomicAdd(&spill_cnt[1], 1);
               if (p < SPILL_CAP) spill_s[p] = s; }
    }
}

// ---------- per-bin counting sort -> exact CSR, fused out-degree ----------
__global__ void k_binsort(const int* __restrict__ dpairs, const int* __restrict__ cntd,
                          const unsigned char* __restrict__ srcb, const int* __restrict__ cnts,
                          int* __restrict__ adj, int* __restrict__ rptr,
                          int* __restrict__ rcnt, int* __restrict__ deg,
                          int N, int CAPB) {
    __shared__ int h[BINW];    // per-local-node in-degree
    __shared__ int o[BINW];    // exclusive scan
    __shared__ int rk[BINW];   // placement cursors
    __shared__ int hd[BINW];   // out-degree histogram
    int bin = blockIdx.x;
    int t = threadIdx.x;
    h[t] = 0; rk[t] = 0; hd[t] = 0;
    __syncthreads();
    int m = cntd[bin]; if (m > CAPB) m = CAPB;
    const int* pp = dpairs + (size_t)bin * CAPB;
    for (int i = t; i < m; i += blockDim.x)
        atomicAdd(&h[((unsigned)pp[i]) >> 24], 1);
    // out-degree from src-binned local ids (independent of h)
    int ms = cnts[bin]; if (ms > CAPB) ms = CAPB;
    const unsigned char* sp = srcb + (size_t)bin * CAPB;
    for (int i = t; i < ms; i += blockDim.x)
        atomicAdd(&hd[sp[i]], 1);
    __syncthreads();
    // inclusive scan of h over 256 entries
    o[t] = h[t];
    __syncthreads();
    for (int s = 1; s < BINW; s <<= 1) {
        int v = 0;
        if (t >= s) v = o[t - s];
        __syncthreads();
        if (t >= s) o[t] += v;
        __syncthreads();
    }
    int binbase = bin * CAPB;
    {
        int excl = o[t] - h[t];
        o[t] = excl;
        int n = (bin << BBITS) + t;
        if (n < N) { rptr[n] = binbase + excl; rcnt[n] = h[t]; deg[n] = hd[t]; }
    }
    __syncthreads();
    for (int i = t; i < m; i += blockDim.x) {
        int w = pp[i];
        int dl = ((unsigned)w) >> 24;
        int s  = w & 0xFFFFFF;
        int r = atomicAdd(&rk[dl], 1);
        adj[binbase + o[dl] + r] = s;
    }
}

__global__ void k_deg_spill(const int* __restrict__ spill_cnt, const int* __restrict__ spill_s,
                            int* __restrict__ deg) {
    int total = spill_cnt[1]; if (total > SPILL_CAP) total = SPILL_CAP;
    int stride = gridDim.x * blockDim.x;
    for (int i = blockIdx.x * blockDim.x + threadIdx.x; i < total; i += stride)
        atomicAdd(&deg[spill_s[i]], 1);
}

// ---------- x [T][N] -> xt [N][T] ----------
__global__ void k_tin(const float* __restrict__ x, float* __restrict__ xt, int N) {
    int n = blockIdx.x * blockDim.x + threadIdx.x;
    if (n >= N) return;
    float v[TCH];
#pragma unroll
    for (int t = 0; t < TCH; ++t) v[t] = x[(size_t)t * N + n];
    float4* o = reinterpret_cast<float4*>(xt + (size_t)n * TCH);
    o[0] = make_float4(v[0],  v[1],  v[2],  v[3]);
    o[1] = make_float4(v[4],  v[5],  v[6],  v[7]);
    o[2] = make_float4(v[8],  v[9],  v[10], v[11]);
    o[3] = make_float4(v[12], v[13], v[14], v[15]);
}

// ---------- layer: pull over CSR + fused combine ----------
// 4 threads per node, one float4 quarter each; 8-wide unrolled gather.
__global__ void k_layer(const float* __restrict__ xin, float* __restrict__ xout,
                        const int* __restrict__ rptr, const int* __restrict__ rcnt,
                        const int* __restrict__ adj, const int* __restrict__ deg,
                        const float* __restrict__ a1p, const float* __restrict__ gp,
                        const float* __restrict__ bp, int l, int N,
                        int last, float* __restrict__ out) {
    int tt = blockIdx.x * blockDim.x + threadIdx.x;
    int n = tt >> 2;
    int q = tt & 3;
    if (n >= N) return;
    float a1 = a1p[l], g = gp[l], bi = bp[l];
    float dp = 1.0f / (1.0f + expf(-g));
    float sw = expf(a1);
    float nw = sw * tanhf(a1);

    int b = rptr[n], m = rcnt[n];
    const int* row = adj + b;
    float4 acc0 = make_float4(0.f, 0.f, 0.f, 0.f);
    float4 acc1 = make_float4(0.f, 0.f, 0.f, 0.f);
    float4 acc2 = make_float4(0.f, 0.f, 0.f, 0.f);
    float4 acc3 = make_float4(0.f, 0.f, 0.f, 0.f);
    int i = 0;
    for (; i + 7 < m; i += 8) {
        int s0 = row[i],     s1 = row[i + 1], s2 = row[i + 2], s3 = row[i + 3];
        int s4 = row[i + 4], s5 = row[i + 5], s6 = row[i + 6], s7 = row[i + 7];
        float4 x0 = reinterpret_cast<const float4*>(xin + (size_t)s0 * TCH)[q];
        float4 x1 = reinterpret_cast<const float4*>(xin + (size_t)s1 * TCH)[q];
        float4 x2 = reinterpret_cast<const float4*>(xin + (size_t)s2 * TCH)[q];
        float4 x3 = reinterpret_cast<const float4*>(xin + (size_t)s3 * TCH)[q];
        float4 x4 = reinterpret_cast<const float4*>(xin + (size_t)s4 * TCH)[q];
        float4 x5 = reinterpret_cast<const float4*>(xin + (size_t)s5 * TCH)[q];
        float4 x6 = reinterpret_cast<const float4*>(xin + (size_t)s6 * TCH)[q];
        float4 x7 = reinterpret_cast<const float4*>(xin + (size_t)s7 * TCH)[q];
        acc0.x += x0.x; acc0.y += x0.y; acc0.z += x0.z; acc0.w += x0.w;
        acc1.x += x1.x; acc1.y += x1.y; acc1.z += x1.z; acc1.w += x1.w;
        acc2.x += x2.x; acc2.y += x2.y; acc2.z += x2.z; acc2.w += x2.w;
        acc3.x += x3.x; acc3.y += x3.y; acc3.z += x3.z; acc3.w += x3.w;
        acc0.x += x4.x; acc0.y += x4.y; acc0.z += x4.z; acc0.w += x4.w;
        acc1.x += x5.x; acc1.y += x5.y; acc1.z += x5.z; acc1.w += x5.w;
        acc2.x += x6.x; acc2.y += x6.y; acc2.z += x6.z; acc2.w += x6.w;
        acc3.x += x7.x; acc3.y += x7.y; acc3.z += x7.z; acc3.w += x7.w;
    }
    for (; i < m; ++i) {
        int s0 = row[i];
        float4 x0 = reinterpret_cast<const float4*>(xin + (size_t)s0 * TCH)[q];
        acc0.x += x0.x; acc0.y += x0.y; acc0.z += x0.z; acc0.w += x0.w;
    }
    acc0.x += acc1.x + acc2.x + acc3.x;
    acc0.y += acc1.y + acc2.y + acc3.y;
    acc0.z += acc1.z + acc2.z + acc3.z;
    acc0.w += acc1.w + acc2.w + acc3.w;

    float ldg = logf((float)deg[n]);
    float cs = sw * expf(dp * ldg);
    float cn = nw * expf((dp - 1.0f) * ldg);

    float4 xq = reinterpret_cast<const float4*>(xin + (size_t)n * TCH)[q];
    float4 r;
    r.x = cs * xq.x + cn * acc0.x + bi;
    r.y = cs * xq.y + cn * acc0.y + bi;
    r.z = cs * xq.z + cn * acc0.z + bi;
    r.w = cs * xq.w + cn * acc0.w + bi;

    if (last) {
        int t0 = q * 4;
        out[(size_t)(t0 + 0) * N + n] = r.x;
        out[(size_t)(t0 + 1) * N + n] = r.y;
        out[(size_t)(t0 + 2) * N + n] = r.z;
        out[(size_t)(t0 + 3) * N + n] = r.w;
    } else {
        reinterpret_cast<float4*>(xout + (size_t)n * TCH)[q] = r;
    }
}

// ---------- fix-up for spilled dst edges (normally empty) ----------
__global__ void k_spill(const int* __restrict__ spill_cnt, const int* __restrict__ spill_d,
                        const float* __restrict__ xin, float* __restrict__ xout,
                        const int* __restrict__ deg,
                        const float* __restrict__ a1p, const float* __restrict__ gp,
                        int l, int N, int last, float* __restrict__ out) {
    int total = spill_cnt[0]; if (total > SPILL_CAP) total = SPILL_CAP;
    int stride = gridDim.x * blockDim.x;
    float a1 = a1p[l], g = gp[l];
    float dp = 1.0f / (1.0f + expf(-g));
    float nw = expf(a1) * tanhf(a1);
    for (int p = blockIdx.x * blockDim.x + threadIdx.x; p < total; p += stride) {
        int d = spill_d[2 * p], s = spill_d[2 * p + 1];
        float cn = nw * expf((dp - 1.0f) * logf((float)deg[d]));
#pragma unroll
        for (int t = 0; t < TCH; ++t) {
            float v = cn * xin[(size_t)s * TCH + t];
            if (last) atomicAdd(&out[(size_t)t * N + d], v);
            else      atomicAdd(&xout[(size_t)d * TCH + t], v);
        }
    }
}

extern "C" void kernel_launch(void* const* d_in, const int* in_sizes, int n_in,
                              void* d_out, int out_size, void* d_ws, size_t ws_size,
                              hipStream_t stream) {
    const float* x      = (const float*)d_in[0];
    const int*   ei     = (const int*)d_in[1];
    const float* alpha1 = (const float*)d_in[2];
    // d_in[3] = alpha2: UNUSED (reference's alpha2 property returns alpha1)
    const float* gamma  = (const float*)d_in[4];
    const float* bias   = (const float*)d_in[5];
    float* out = (float*)d_out;

    const int N = in_sizes[0] / TCH;
    const int E = in_sizes[1] / 2;
    const int L = in_sizes[2];
    const int* src = ei;
    const int* dst = ei + E;

    const int NB = (N + BINW - 1) >> BBITS;
    int CHUNK = 4096;
    int NBLK = (E + CHUNK - 1) / CHUNK;
    while (NBLK > 4 * BLK) { CHUNK *= 2; NBLK = (E + CHUNK - 1) / CHUNK; }

    auto align = [](size_t v) { return (v + 255) & ~(size_t)255; };
    char* ws = (char*)d_ws;
    size_t off = 0;
    int* deg     = (int*)(ws + off); off += align((size_t)N * 4);
    int* rptr    = (int*)(ws + off); off += align((size_t)N * 4);
    int* rcnt    = (int*)(ws + off); off += align((size_t)N * 4);
    int* cntd    = (int*)(ws + off); off += align((size_t)NB * 4);
    int* cnts    = (int*)(ws + off); off += align((size_t)NB * 4);
    int* Hd      = (int*)(ws + off); off += align((size_t)NBLK * NB * 4);
    int* Hs      = (int*)(ws + off); off += align((size_t)NBLK * NB * 4);
    int* offd    = (int*)(ws + off); off += align((size_t)NBLK * NB * 4);
    int* offs    = (int*)(ws + off); off += align((size_t)NBLK * NB * 4);
    int* spill_c = (int*)(ws + off); off += 256;
    int* spill_d = (int*)(ws + off); off += align((size_t)SPILL_CAP * 8);
    int* spill_s = (int*)(ws + off); off += align((size_t)SPILL_CAP * 4);
    float* xt0   = (float*)(ws + off); off += align((size_t)N * TCH * 4);
    float* xt1   = (float*)(ws + off); off += align((size_t)N * TCH * 4);
    // bin capacity: avg + slack, clamped to fit remaining workspace
    long long avg = ((long long)E * BINW + N - 1) / N;     // ~8192
    int CAPB = (int)(avg + avg / 16 + 64);
    size_t rem = (ws_size > off) ? (ws_size - off) : 0;
    size_t cap_fit = rem / ((size_t)NB * 9 + 8);           // dpairs4 + adj4 + srcb1
    if ((size_t)CAPB > cap_fit) CAPB = (int)cap_fit;
    if (CAPB < 1) CAPB = 1;
    int* dpairs  = (int*)(ws + off); off += align((size_t)NB * CAPB * 4);
    int* adj     = (int*)(ws + off); off += align((size_t)NB * CAPB * 4);
    unsigned char* srcb = (unsigned char*)(ws + off);

    dim3 b(BLK), gN((N + BLK - 1) / BLK);
    dim3 gN4(((size_t)N * 4 + BLK - 1) / BLK);

    hipMemsetAsync(spill_c, 0, 256, stream);
    k_hist   <<<dim3(NBLK), b, 2 * NB * 4, stream>>>(src, dst, Hd, Hs, E, NB, CHUNK);
    k_scanb  <<<dim3(NB),   b, 0,          stream>>>(Hd, offd, cntd, NB, NBLK);
    k_scanb  <<<dim3(NB),   b, 0,          stream>>>(Hs, offs, cnts, NB, NBLK);
    k_place  <<<dim3(NBLK), b, 4 * NB * 4, stream>>>(src, dst, offd, offs, dpairs, srcb,
                                                     spill_c, spill_d, spill_s,
                                                     E, NB, CHUNK, CAPB);
    k_binsort<<<dim3(NB),   b, 0,          stream>>>(dpairs, cntd, srcb, cnts,
                                                     adj, rptr, rcnt, deg, N, CAPB);
    k_deg_spill<<<dim3(16), b, 0,          stream>>>(spill_c, spill_s, deg);
    k_tin    <<<gN,         b, 0,          stream>>>(x, xt0, N);

    float* xin = xt0;
    float* xo  = xt1;
    for (int l = 0; l < L; ++l) {
        int last = (l == L - 1) ? 1 : 0;
        k_layer<<<gN4, b, 0, stream>>>(xin, xo, rptr, rcnt, adj, deg,
                                       alpha1, gamma, bias, l, N, last, out);
        k_spill<<<dim3(16), b, 0, stream>>>(spill_c, spill_d, xin, xo, deg,
                                            alpha1, gamma, l, N, last, out);
        float* tmp = xin; xin = xo; xo = tmp;
    }
}

// Round 7
// 198.438 us; speedup vs baseline: 4.1220x; 1.2083x over previous
//
#include <hip/hip_runtime.h>

// DGMRF forward, L layers, T=16 channels.
// Binned counting-sort build (no global atomics) -> exact per-node CSR ->
// PULL layers (register accumulation, no atomics on the hot path).
//
// Layer math (factored): S[d] = sum_{e: dst(e)=d} x[src(e)]  (unweighted)
//   x_new[n] = sw * x[n] * deg[n]^dp + nw * S[n] * deg[n]^(dp-1) + bias
// dp = sigmoid(gamma[l]), sw = exp(alpha1[l]), nw = sw * tanh(alpha1[l]).
// deg = OUT-degree over edge_index[0].
//
// k_place does an in-LDS counting sort of each 4096-edge chunk by bin and
// then writes bin-sorted runs with consecutive lanes -> consecutive addresses,
// so scattered 4B/1B element writes become ~2 sectors per ~10-entry run
// (round-6 profile: unsorted scatter flushed one 32B sector PER ELEMENT,
// WRITE_SIZE 162MB for 16MB payload).

#define TCH 16
#define BBITS 8
#define BINW (1 << BBITS)      // 256 nodes per bin
#define BLK 256
#define SPILL_CAP 65536

// ---------- per-block bin histograms (dst and src) ----------
__global__ void k_hist(const int* __restrict__ src, const int* __restrict__ dst,
                       int* __restrict__ Hd, int* __restrict__ Hs,
                       int E, int NB, int CHUNK) {
    extern __shared__ int sm[];                 // cd[NB], cs[NB]
    int* cd = sm; int* cs2 = sm + NB;
    for (int i = threadIdx.x; i < 2 * NB; i += blockDim.x) sm[i] = 0;
    __syncthreads();
    int beg = blockIdx.x * CHUNK;
    int end = beg + CHUNK; if (end > E) end = E;
    for (int i = beg + threadIdx.x; i < end; i += blockDim.x) {
        atomicAdd(&cd[dst[i] >> BBITS], 1);
        atomicAdd(&cs2[src[i] >> BBITS], 1);
    }
    __syncthreads();
    int* hd = Hd + (size_t)blockIdx.x * NB;
    int* hs = Hs + (size_t)blockIdx.x * NB;
    for (int b = threadIdx.x; b < NB; b += blockDim.x) { hd[b] = cd[b]; hs[b] = cs2[b]; }
}

// ---------- column scan over blocks, one block per bin (NBLK <= 4*BLK) ----
__global__ void k_scanb(const int* __restrict__ H, int* __restrict__ off,
                        int* __restrict__ cnt, int NB, int NBLK) {
    __shared__ int ss[BLK];
    int bin = blockIdx.x;
    int t = threadIdx.x;
    int v[4];
    int sum = 0;
#pragma unroll
    for (int j = 0; j < 4; ++j) {
        int b = t * 4 + j;
        v[j] = (b < NBLK) ? H[(size_t)b * NB + bin] : 0;
        sum += v[j];
    }
    ss[t] = sum;
    __syncthreads();
    for (int o = 1; o < BLK; o <<= 1) {
        int u = (t >= o) ? ss[t - o] : 0;
        __syncthreads();
        ss[t] += u;
        __syncthreads();
    }
    int base = ss[t] - sum;                      // exclusive over 4-groups
#pragma unroll
    for (int j = 0; j < 4; ++j) {
        int b = t * 4 + j;
        if (b < NBLK) off[(size_t)b * NB + bin] = base;
        base += v[j];
    }
    if (t == BLK - 1) cnt[bin] = ss[BLK - 1];
}

// ---------- place edges: in-LDS counting sort + coalesced run writes ------
// Requires NB <= 2*BLK (one scan pass, 2 slots/thread).
__global__ __launch_bounds__(BLK) void k_place(
        const int* __restrict__ src, const int* __restrict__ dst,
        const int* __restrict__ offd, const int* __restrict__ offs,
        int* __restrict__ dpairs, unsigned char* __restrict__ srcb,
        int* __restrict__ spill_cnt, int* __restrict__ spill_d,
        int* __restrict__ spill_s,
        int E, int NB, int CHUNK, int CAPB) {
    __shared__ int ss[BLK];
    extern __shared__ int sm[];
    int* cur = sm;                     // [NB]  hist -> cursor
    int* gdl = sm + NB;                // [NB]  global-addr delta per bin
    int* pay = sm + 2 * NB;            // [CHUNK] payload (sorted)
    int* ga  = sm + 2 * NB + CHUNK;    // [CHUNK] global address (sorted)

    int t = threadIdx.x;
    int beg = blockIdx.x * CHUNK;
    int end = beg + CHUNK; if (end > E) end = E;
    int m = end - beg;

    // ================= dst pass =================
    for (int i = t; i < NB; i += BLK) cur[i] = 0;
    __syncthreads();
    for (int i = beg + t; i < end; i += BLK)
        atomicAdd(&cur[dst[i] >> BBITS], 1);
    __syncthreads();
    // exclusive scan over NB (2 slots per thread)
    int c0 = (2 * t     < NB) ? cur[2 * t]     : 0;
    int c1 = (2 * t + 1 < NB) ? cur[2 * t + 1] : 0;
    ss[t] = c0 + c1;
    __syncthreads();
    for (int o = 1; o < BLK; o <<= 1) {
        int v = (t >= o) ? ss[t - o] : 0;
        __syncthreads();
        ss[t] += v;
        __syncthreads();
    }
    int excl = ss[t] - (c0 + c1);
    __syncthreads();                   // all reads of cur done before overwrite
    if (2 * t < NB) {
        int od = offd[(size_t)blockIdx.x * NB + 2 * t];
        cur[2 * t] = excl;
        gdl[2 * t] = 2 * t * CAPB + od - excl;
    }
    if (2 * t + 1 < NB) {
        int od = offd[(size_t)blockIdx.x * NB + 2 * t + 1];
        cur[2 * t + 1] = excl + c0;
        gdl[2 * t + 1] = (2 * t + 1) * CAPB + od - (excl + c0);
    }
    __syncthreads();
    for (int i = beg + t; i < end; i += BLK) {
        int d = dst[i], s = src[i];
        int bd = d >> BBITS;
        int ls = atomicAdd(&cur[bd], 1);           // final sorted local slot
        int g  = gdl[bd] + ls;                     // = bd*CAPB + od + rank
        if (g < (bd + 1) * CAPB) {
            pay[ls] = ((d & (BINW - 1)) << 24) | s;
            ga[ls] = g;
        } else {
            ga[ls] = -1;
            int p = atomicAdd(&spill_cnt[0], 1);
            if (p < SPILL_CAP) { spill_d[2 * p] = d; spill_d[2 * p + 1] = s; }
        }
    }
    __syncthreads();
    for (int i = t; i < m; i += BLK) {             // coalesced run writes
        int g = ga[i];
        if (g >= 0) dpairs[g] = pay[i];
    }
    __syncthreads();

    // ================= src pass (reuses LDS) =================
    unsigned char* payb = (unsigned char*)pay;
    for (int i = t; i < NB; i += BLK) cur[i] = 0;
    __syncthreads();
    for (int i = beg + t; i < end; i += BLK)
        atomicAdd(&cur[src[i] >> BBITS], 1);
    __syncthreads();
    c0 = (2 * t     < NB) ? cur[2 * t]     : 0;
    c1 = (2 * t + 1 < NB) ? cur[2 * t + 1] : 0;
    ss[t] = c0 + c1;
    __syncthreads();
    for (int o = 1; o < BLK; o <<= 1) {
        int v = (t >= o) ? ss[t - o] : 0;
        __syncthreads();
        ss[t] += v;
        __syncthreads();
    }
    excl = ss[t] - (c0 + c1);
    __syncthreads();
    if (2 * t < NB) {
        int os_ = offs[(size_t)blockIdx.x * NB + 2 * t];
        cur[2 * t] = excl;
        gdl[2 * t] = 2 * t * CAPB + os_ - excl;
    }
    if (2 * t + 1 < NB) {
        int os_ = offs[(size_t)blockIdx.x * NB + 2 * t + 1];
        cur[2 * t + 1] = excl + c0;
        gdl[2 * t + 1] = (2 * t + 1) * CAPB + os_ - (excl + c0);
    }
    __syncthreads();
    for (int i = beg + t; i < end; i += BLK) {
        int s = src[i];
        int bs = s >> BBITS;
        int ls = atomicAdd(&cur[bs], 1);
        int g  = gdl[bs] + ls;
        if (g < (bs + 1) * CAPB) {
            payb[ls] = (unsigned char)(s & (BINW - 1));
            ga[ls] = g;
        } else {
            ga[ls] = -1;
            int p = atomicAdd(&spill_cnt[1], 1);
            if (p < SPILL_CAP) spill_s[p] = s;
        }
    }
    __syncthreads();
    for (int i = t; i < m; i += BLK) {
        int g = ga[i];
        if (g >= 0) srcb[g] = payb[i];
    }
}

// ---------- per-bin counting sort -> exact CSR, fused out-degree ----------
__global__ void k_binsort(const int* __restrict__ dpairs, const int* __restrict__ cntd,
                          const unsigned char* __restrict__ srcb, const int* __restrict__ cnts,
                          int* __restrict__ adj, int* __restrict__ rptr,
                          int* __restrict__ rcnt, int* __restrict__ deg,
                          int N, int CAPB) {
    __shared__ int h[BINW];    // per-local-node in-degree
    __shared__ int o[BINW];    // exclusive scan
    __shared__ int rk[BINW];   // placement cursors
    __shared__ int hd[BINW];   // out-degree histogram
    int bin = blockIdx.x;
    int t = threadIdx.x;
    h[t] = 0; rk[t] = 0; hd[t] = 0;
    __syncthreads();
    int m = cntd[bin]; if (m > CAPB) m = CAPB;
    const int* pp = dpairs + (size_t)bin * CAPB;
    for (int i = t; i < m; i += blockDim.x)
        atomicAdd(&h[((unsigned)pp[i]) >> 24], 1);
    // out-degree from src-binned local ids (independent of h)
    int ms = cnts[bin]; if (ms > CAPB) ms = CAPB;
    const unsigned char* sp = srcb + (size_t)bin * CAPB;
    for (int i = t; i < ms; i += blockDim.x)
        atomicAdd(&hd[sp[i]], 1);
    __syncthreads();
    // inclusive scan of h over 256 entries
    o[t] = h[t];
    __syncthreads();
    for (int s = 1; s < BINW; s <<= 1) {
        int v = 0;
        if (t >= s) v = o[t - s];
        __syncthreads();
        if (t >= s) o[t] += v;
        __syncthreads();
    }
    int binbase = bin * CAPB;
    {
        int excl = o[t] - h[t];
        o[t] = excl;
        int n = (bin << BBITS) + t;
        if (n < N) { rptr[n] = binbase + excl; rcnt[n] = h[t]; deg[n] = hd[t]; }
    }
    __syncthreads();
    for (int i = t; i < m; i += blockDim.x) {
        int w = pp[i];
        int dl = ((unsigned)w) >> 24;
        int s  = w & 0xFFFFFF;
        int r = atomicAdd(&rk[dl], 1);
        adj[binbase + o[dl] + r] = s;
    }
}

__global__ void k_deg_spill(const int* __restrict__ spill_cnt, const int* __restrict__ spill_s,
                            int* __restrict__ deg) {
    int total = spill_cnt[1]; if (total > SPILL_CAP) total = SPILL_CAP;
    int stride = gridDim.x * blockDim.x;
    for (int i = blockIdx.x * blockDim.x + threadIdx.x; i < total; i += stride)
        atomicAdd(&deg[spill_s[i]], 1);
}

// ---------- x [T][N] -> xt [N][T] ----------
__global__ void k_tin(const float* __restrict__ x, float* __restrict__ xt, int N) {
    int n = blockIdx.x * blockDim.x + threadIdx.x;
    if (n >= N) return;
    float v[TCH];
#pragma unroll
    for (int t = 0; t < TCH; ++t) v[t] = x[(size_t)t * N + n];
    float4* o = reinterpret_cast<float4*>(xt + (size_t)n * TCH);
    o[0] = make_float4(v[0],  v[1],  v[2],  v[3]);
    o[1] = make_float4(v[4],  v[5],  v[6],  v[7]);
    o[2] = make_float4(v[8],  v[9],  v[10], v[11]);
    o[3] = make_float4(v[12], v[13], v[14], v[15]);
}

// ---------- layer: pull over CSR + fused combine ----------
// 4 threads per node, one float4 quarter each; 8-wide unrolled gather.
__global__ void k_layer(const float* __restrict__ xin, float* __restrict__ xout,
                        const int* __restrict__ rptr, const int* __restrict__ rcnt,
                        const int* __restrict__ adj, const int* __restrict__ deg,
                        const float* __restrict__ a1p, const float* __restrict__ gp,
                        const float* __restrict__ bp, int l, int N,
                        int last, float* __restrict__ out) {
    int tt = blockIdx.x * blockDim.x + threadIdx.x;
    int n = tt >> 2;
    int q = tt & 3;
    if (n >= N) return;
    float a1 = a1p[l], g = gp[l], bi = bp[l];
    float dp = 1.0f / (1.0f + expf(-g));
    float sw = expf(a1);
    float nw = sw * tanhf(a1);

    int b = rptr[n], m = rcnt[n];
    const int* row = adj + b;
    float4 acc0 = make_float4(0.f, 0.f, 0.f, 0.f);
    float4 acc1 = make_float4(0.f, 0.f, 0.f, 0.f);
    float4 acc2 = make_float4(0.f, 0.f, 0.f, 0.f);
    float4 acc3 = make_float4(0.f, 0.f, 0.f, 0.f);
    int i = 0;
    for (; i + 7 < m; i += 8) {
        int s0 = row[i],     s1 = row[i + 1], s2 = row[i + 2], s3 = row[i + 3];
        int s4 = row[i + 4], s5 = row[i + 5], s6 = row[i + 6], s7 = row[i + 7];
        float4 x0 = reinterpret_cast<const float4*>(xin + (size_t)s0 * TCH)[q];
        float4 x1 = reinterpret_cast<const float4*>(xin + (size_t)s1 * TCH)[q];
        float4 x2 = reinterpret_cast<const float4*>(xin + (size_t)s2 * TCH)[q];
        float4 x3 = reinterpret_cast<const float4*>(xin + (size_t)s3 * TCH)[q];
        float4 x4 = reinterpret_cast<const float4*>(xin + (size_t)s4 * TCH)[q];
        float4 x5 = reinterpret_cast<const float4*>(xin + (size_t)s5 * TCH)[q];
        float4 x6 = reinterpret_cast<const float4*>(xin + (size_t)s6 * TCH)[q];
        float4 x7 = reinterpret_cast<const float4*>(xin + (size_t)s7 * TCH)[q];
        acc0.x += x0.x; acc0.y += x0.y; acc0.z += x0.z; acc0.w += x0.w;
        acc1.x += x1.x; acc1.y += x1.y; acc1.z += x1.z; acc1.w += x1.w;
        acc2.x += x2.x; acc2.y += x2.y; acc2.z += x2.z; acc2.w += x2.w;
        acc3.x += x3.x; acc3.y += x3.y; acc3.z += x3.z; acc3.w += x3.w;
        acc0.x += x4.x; acc0.y += x4.y; acc0.z += x4.z; acc0.w += x4.w;
        acc1.x += x5.x; acc1.y += x5.y; acc1.z += x5.z; acc1.w += x5.w;
        acc2.x += x6.x; acc2.y += x6.y; acc2.z += x6.z; acc2.w += x6.w;
        acc3.x += x7.x; acc3.y += x7.y; acc3.z += x7.z; acc3.w += x7.w;
    }
    for (; i < m; ++i) {
        int s0 = row[i];
        float4 x0 = reinterpret_cast<const float4*>(xin + (size_t)s0 * TCH)[q];
        acc0.x += x0.x; acc0.y += x0.y; acc0.z += x0.z; acc0.w += x0.w;
    }
    acc0.x += acc1.x + acc2.x + acc3.x;
    acc0.y += acc1.y + acc2.y + acc3.y;
    acc0.z += acc1.z + acc2.z + acc3.z;
    acc0.w += acc1.w + acc2.w + acc3.w;

    float ldg = logf((float)deg[n]);
    float cs = sw * expf(dp * ldg);
    float cn = nw * expf((dp - 1.0f) * ldg);

    float4 xq = reinterpret_cast<const float4*>(xin + (size_t)n * TCH)[q];
    float4 r;
    r.x = cs * xq.x + cn * acc0.x + bi;
    r.y = cs * xq.y + cn * acc0.y + bi;
    r.z = cs * xq.z + cn * acc0.z + bi;
    r.w = cs * xq.w + cn * acc0.w + bi;

    if (last) {
        int t0 = q * 4;
        out[(size_t)(t0 + 0) * N + n] = r.x;
        out[(size_t)(t0 + 1) * N + n] = r.y;
        out[(size_t)(t0 + 2) * N + n] = r.z;
        out[(size_t)(t0 + 3) * N + n] = r.w;
    } else {
        reinterpret_cast<float4*>(xout + (size_t)n * TCH)[q] = r;
    }
}

// ---------- fix-up for spilled dst edges (normally empty) ----------
__global__ void k_spill(const int* __restrict__ spill_cnt, const int* __restrict__ spill_d,
                        const float* __restrict__ xin, float* __restrict__ xout,
                        const int* __restrict__ deg,
                        const float* __restrict__ a1p, const float* __restrict__ gp,
                        int l, int N, int last, float* __restrict__ out) {
    int total = spill_cnt[0]; if (total > SPILL_CAP) total = SPILL_CAP;
    int stride = gridDim.x * blockDim.x;
    float a1 = a1p[l], g = gp[l];
    float dp = 1.0f / (1.0f + expf(-g));
    float nw = expf(a1) * tanhf(a1);
    for (int p = blockIdx.x * blockDim.x + threadIdx.x; p < total; p += stride) {
        int d = spill_d[2 * p], s = spill_d[2 * p + 1];
        float cn = nw * expf((dp - 1.0f) * logf((float)deg[d]));
#pragma unroll
        for (int t = 0; t < TCH; ++t) {
            float v = cn * xin[(size_t)s * TCH + t];
            if (last) atomicAdd(&out[(size_t)t * N + d], v);
            else      atomicAdd(&xout[(size_t)d * TCH + t], v);
        }
    }
}

extern "C" void kernel_launch(void* const* d_in, const int* in_sizes, int n_in,
                              void* d_out, int out_size, void* d_ws, size_t ws_size,
                              hipStream_t stream) {
    const float* x      = (const float*)d_in[0];
    const int*   ei     = (const int*)d_in[1];
    const float* alpha1 = (const float*)d_in[2];
    // d_in[3] = alpha2: UNUSED (reference's alpha2 property returns alpha1)
    const float* gamma  = (const float*)d_in[4];
    const float* bias   = (const float*)d_in[5];
    float* out = (float*)d_out;

    const int N = in_sizes[0] / TCH;
    const int E = in_sizes[1] / 2;
    const int L = in_sizes[2];
    const int* src = ei;
    const int* dst = ei + E;

    const int NB = (N + BINW - 1) >> BBITS;
    int CHUNK = 4096;
    int NBLK = (E + CHUNK - 1) / CHUNK;
    while (NBLK > 4 * BLK) { CHUNK *= 2; NBLK = (E + CHUNK - 1) / CHUNK; }

    auto align = [](size_t v) { return (v + 255) & ~(size_t)255; };
    char* ws = (char*)d_ws;
    size_t off = 0;
    int* deg     = (int*)(ws + off); off += align((size_t)N * 4);
    int* rptr    = (int*)(ws + off); off += align((size_t)N * 4);
    int* rcnt    = (int*)(ws + off); off += align((size_t)N * 4);
    int* cntd    = (int*)(ws + off); off += align((size_t)NB * 4);
    int* cnts    = (int*)(ws + off); off += align((size_t)NB * 4);
    int* Hd      = (int*)(ws + off); off += align((size_t)NBLK * NB * 4);
    int* Hs      = (int*)(ws + off); off += align((size_t)NBLK * NB * 4);
    int* offd    = (int*)(ws + off); off += align((size_t)NBLK * NB * 4);
    int* offs    = (int*)(ws + off); off += align((size_t)NBLK * NB * 4);
    int* spill_c = (int*)(ws + off); off += 256;
    int* spill_d = (int*)(ws + off); off += align((size_t)SPILL_CAP * 8);
    int* spill_s = (int*)(ws + off); off += align((size_t)SPILL_CAP * 4);
    float* xt0   = (float*)(ws + off); off += align((size_t)N * TCH * 4);
    float* xt1   = (float*)(ws + off); off += align((size_t)N * TCH * 4);
    // bin capacity: avg + slack, clamped to fit remaining workspace
    long long avg = ((long long)E * BINW + N - 1) / N;     // ~8192
    int CAPB = (int)(avg + avg / 16 + 64);
    size_t rem = (ws_size > off) ? (ws_size - off) : 0;
    size_t cap_fit = rem / ((size_t)NB * 9 + 8);           // dpairs4 + adj4 + srcb1
    if ((size_t)CAPB > cap_fit) CAPB = (int)cap_fit;
    if (CAPB < 1) CAPB = 1;
    int* dpairs  = (int*)(ws + off); off += align((size_t)NB * CAPB * 4);
    int* adj     = (int*)(ws + off); off += align((size_t)NB * CAPB * 4);
    unsigned char* srcb = (unsigned char*)(ws + off);

    dim3 b(BLK), gN((N + BLK - 1) / BLK);
    dim3 gN4(((size_t)N * 4 + BLK - 1) / BLK);

    size_t place_lds = ((size_t)2 * NB + 2 * CHUNK) * 4;

    hipMemsetAsync(spill_c, 0, 256, stream);
    k_hist   <<<dim3(NBLK), b, 2 * NB * 4, stream>>>(src, dst, Hd, Hs, E, NB, CHUNK);
    k_scanb  <<<dim3(NB),   b, 0,          stream>>>(Hd, offd, cntd, NB, NBLK);
    k_scanb  <<<dim3(NB),   b, 0,          stream>>>(Hs, offs, cnts, NB, NBLK);
    k_place  <<<dim3(NBLK), b, place_lds,  stream>>>(src, dst, offd, offs, dpairs, srcb,
                                                     spill_c, spill_d, spill_s,
                                                     E, NB, CHUNK, CAPB);
    k_binsort<<<dim3(NB),   b, 0,          stream>>>(dpairs, cntd, srcb, cnts,
                                                     adj, rptr, rcnt, deg, N, CAPB);
    k_deg_spill<<<dim3(16), b, 0,          stream>>>(spill_c, spill_s, deg);
    k_tin    <<<gN,         b, 0,          stream>>>(x, xt0, N);

    float* xin = xt0;
    float* xo  = xt1;
    for (int l = 0; l < L; ++l) {
        int last = (l == L - 1) ? 1 : 0;
        k_layer<<<gN4, b, 0, stream>>>(xin, xo, rptr, rcnt, adj, deg,
                                       alpha1, gamma, bias, l, N, last, out);
        k_spill<<<dim3(16), b, 0, stream>>>(spill_c, spill_d, xin, xo, deg,
                                            alpha1, gamma, l, N, last, out);
        float* tmp = xin; xin = xo; xo = tmp;
    }
}